// Round 2
// baseline (33228.357 us; speedup 1.0000x reference)
//
#include <hip/hip_runtime.h>
#include <math.h>

// Problem constants (match reference)
#define BB   16384
#define NOBS 512
#define NACT 64
#define DIN  1090      // 512+64+512+1+1
#define K0P  1120      // DIN padded to multiple of 32 (zeros)
#define HH   4096
#define DD   1024
#define KC   512

#define MC   2048      // batch chunk rows for the MLP
#define NCH  (BB / MC) // 8 chunks

#define F_DECAY 0.99f
#define F_OMD   0.01f
#define F_CC    0.25f
#define F_EPS   1e-5f

// fp32 emulation via fp16x2 split, 3 MFMA products (hh, hm, mh; mm dropped).
// W is pre-scaled by WSCALE (exact pow2) so fp16 high parts are O(1);
// residuals are scaled by RSCALE (exact pow2) to stay in fp16 NORMAL range
// and accumulated in a second accumulator: x*w = (acc0 + acc1/RSCALE)/WSCALE.
#define WSCALE   64.0f
#define WINV     0.015625f       // 1/64
#define RSCALE   2048.0f
#define RINV     4.8828125e-4f   // 1/2048

using half8 = __attribute__((ext_vector_type(8))) _Float16;  // MFMA A/B frag (4 VGPRs)
using half4 = __attribute__((ext_vector_type(4))) _Float16;  // 8B LDS store
using f4v   = __attribute__((ext_vector_type(4))) float;     // MFMA C/D frag

static __device__ inline void split2(float x, _Float16& h, _Float16& m) {
  h = (_Float16)x;                              // RNE
  m = (_Float16)((x - (float)h) * RSCALE);      // x-h exact in fp32; *2048 exact
}

// ------------------------------------------------------------------
// Build one chunk of X0 = hstack(obs, action, next_obs, reward, term), padded.
// ------------------------------------------------------------------
__global__ __launch_bounds__(256) void build_x0_kernel(
    const float* __restrict__ obs, const float* __restrict__ act,
    const float* __restrict__ nobs, const float* __restrict__ rew,
    const float* __restrict__ term, float* __restrict__ X0)
{
  const int i = blockIdx.x;
  const int t = threadIdx.x;
  float* row = X0 + (size_t)i * K0P;
  for (int c = t; c < K0P; c += 256) {
    float v;
    if (c < NOBS)                 v = obs[(size_t)i * NOBS + c];
    else if (c < NOBS + NACT)     v = act[(size_t)i * NACT + (c - NOBS)];
    else if (c < 2*NOBS + NACT)   v = nobs[(size_t)i * NOBS + (c - NOBS - NACT)];
    else if (c == 1088)           v = rew[i];
    else if (c == 1089)           v = term[i];
    else                          v = 0.0f;
    row[c] = v;
  }
}

__global__ void init_kernel(int* __restrict__ cnt, float* __restrict__ lsum)
{
  const int t = threadIdx.x;
  if (t < KC) cnt[t] = 0;
  if (t == 0) *lsum = 0.0f;
}

__global__ __launch_bounds__(256) void zero_kernel(float* __restrict__ p, int n)
{
  const int i = blockIdx.x * 256 + threadIdx.x;
  if (i < n) p[i] = 0.0f;
}

// ------------------------------------------------------------------
// Emulated-fp32 GEMM via fp16x2 split + MFMA (3 products):
// C[m,n] = act( sum_k A[m,k]*W[k,n] + bias[n] )
// A: [M,K] fp32 row-major, W: [K,N] fp32 row-major (rows >= Kreal read as 0).
// Structure is IDENTICAL to the proven bf16x3 kernel (register-staged
// loads, 2 barriers, compiler-pipelined): only the split arithmetic and
// plane/product count changed (3 planes/6 MFMA -> 2 planes/3 MFMA).
// BM=BN=128, BK=32, 256 threads (4 waves, 2x2), wave tile 64x64 =
// 4x4 of 16x16x32 MFMA tiles. LDS: [comp][kgroup][row][8] f16, k-contiguous
// per lane (16B/lane ds_read_b128).
// ------------------------------------------------------------------
template<bool RELU>
__global__ __launch_bounds__(256, 2) void gemm_f16x2_kernel(
    const float* __restrict__ A, const float* __restrict__ W,
    const float* __restrict__ bias, float* __restrict__ C,
    int M, int N, int K, int Kreal)
{
  __shared__ __align__(16) _Float16 Alds[2][4][128][8];   // 16 KB
  __shared__ __align__(16) _Float16 Blds[2][4][128][8];   // 16 KB

  const int tid = threadIdx.x;
  const int n0 = blockIdx.x * 128;
  const int m0 = blockIdx.y * 128;

  const int sam = tid >> 1;          // A row 0..127
  const int sah = tid & 1;           // A k-half (16 floats each)
  const int sbn = tid & 127;         // B col 0..127
  const int sbq = tid >> 7;          // B k-half

  const int lane = tid & 63;
  const int wv   = tid >> 6;             // wave 0..3 (2x2)
  const int wmo  = (wv >> 1) * 64;
  const int wno  = (wv & 1) * 64;
  const int lm   = lane & 15;            // m (A) / n (B) / col (C)
  const int kg   = lane >> 4;            // k-group 0..3 (8 k each)

  f4v acc0[4][4], acc1[4][4];
  #pragma unroll
  for (int a = 0; a < 4; ++a)
    #pragma unroll
    for (int b = 0; b < 4; ++b) { acc0[a][b] = (f4v)0.0f; acc1[a][b] = (f4v)0.0f; }

  for (int k0 = 0; k0 < K; k0 += 32) {
    float4 av[4];
    #pragma unroll
    for (int q = 0; q < 4; ++q)
      av[q] = *(const float4*)(A + (size_t)(m0 + sam) * K + k0 + sah * 16 + q * 4);
    float bv[16];
    #pragma unroll
    for (int i = 0; i < 16; ++i) {
      const int kk = k0 + sbq * 16 + i;
      bv[i] = (kk < Kreal) ? W[(size_t)kk * N + n0 + sbn] * WSCALE : 0.0f;
    }

    __syncthreads();

    #pragma unroll
    for (int q = 0; q < 4; ++q) {
      const float xs[4] = {av[q].x, av[q].y, av[q].z, av[q].w};
      half4 hh, mm;
      #pragma unroll
      for (int j = 0; j < 4; ++j) {
        _Float16 h, m; split2(xs[j], h, m);
        hh[j] = h; mm[j] = m;
      }
      const int kgi = sah * 2 + (q >> 1);
      const int j0  = (q & 1) * 4;
      *(half4*)&Alds[0][kgi][sam][j0] = hh;
      *(half4*)&Alds[1][kgi][sam][j0] = mm;
    }
    #pragma unroll
    for (int g = 0; g < 2; ++g) {
      half8 vh, vm;
      #pragma unroll
      for (int j = 0; j < 8; ++j) {
        _Float16 h, m; split2(bv[g * 8 + j], h, m);
        vh[j] = h; vm[j] = m;
      }
      const int kgi = sbq * 2 + g;
      *(half8*)&Blds[0][kgi][sbn][0] = vh;
      *(half8*)&Blds[1][kgi][sbn][0] = vm;
    }
    __syncthreads();

    half8 bh[4], bm[4];
    #pragma unroll
    for (int nt = 0; nt < 4; ++nt) {
      bh[nt] = *(const half8*)&Blds[0][kg][wno + nt * 16 + lm][0];
      bm[nt] = *(const half8*)&Blds[1][kg][wno + nt * 16 + lm][0];
    }
    #pragma unroll
    for (int mt = 0; mt < 4; ++mt) {
      const half8 ah = *(const half8*)&Alds[0][kg][wmo + mt * 16 + lm][0];
      const half8 am = *(const half8*)&Alds[1][kg][wmo + mt * 16 + lm][0];
      #pragma unroll
      for (int nt = 0; nt < 4; ++nt) {
        acc0[mt][nt] = __builtin_amdgcn_mfma_f32_16x16x32_f16(ah, bh[nt], acc0[mt][nt], 0, 0, 0); // hi*hi
        acc1[mt][nt] = __builtin_amdgcn_mfma_f32_16x16x32_f16(ah, bm[nt], acc1[mt][nt], 0, 0, 0); // hi*res
        acc1[mt][nt] = __builtin_amdgcn_mfma_f32_16x16x32_f16(am, bh[nt], acc1[mt][nt], 0, 0, 0); // res*hi
      }
    }
  }

  float bias_v[4];
  #pragma unroll
  for (int nt = 0; nt < 4; ++nt) bias_v[nt] = bias[n0 + wno + nt * 16 + lm];

  #pragma unroll
  for (int mt = 0; mt < 4; ++mt)
    #pragma unroll
    for (int nt = 0; nt < 4; ++nt) {
      const int n = n0 + wno + nt * 16 + lm;
      #pragma unroll
      for (int r = 0; r < 4; ++r) {
        const int m = m0 + wmo + mt * 16 + kg * 4 + r;
        float v = (acc0[mt][nt][r] + acc1[mt][nt][r] * RINV) * WINV + bias_v[nt];
        if (RELU) v = fmaxf(v, 0.0f);
        C[(size_t)m * N + n] = v;
      }
    }
}

// ------------------------------------------------------------------
// fp32 vector GEMM (scores GEMM only)
// ------------------------------------------------------------------
__global__ __launch_bounds__(256) void sgemm_kernel(
    const float* __restrict__ A, const float* __restrict__ W,
    const float* __restrict__ bias, float* __restrict__ C,
    int M, int N, int K, int Kreal, float alpha)
{
  __shared__ float As[16][128];
  __shared__ float Bs[16][128];

  const int tid = threadIdx.x;
  const int n0 = blockIdx.x * 128;
  const int m0 = blockIdx.y * 128;

  const int ar = tid & 63;
  const int ak = (tid >> 6) << 2;
  const int bk = tid >> 5;
  const int bc = (tid & 31) << 2;
  const int tx = tid & 15;
  const int ty = tid >> 4;

  float acc[2][2][4][4];
  #pragma unroll
  for (int a = 0; a < 2; ++a)
    #pragma unroll
    for (int b = 0; b < 2; ++b)
      #pragma unroll
      for (int c = 0; c < 4; ++c)
        #pragma unroll
        for (int d = 0; d < 4; ++d) acc[a][b][c][d] = 0.0f;

  const float4 zero4 = make_float4(0.f, 0.f, 0.f, 0.f);

  for (int k0 = 0; k0 < K; k0 += 16) {
    float4 a0 = *(const float4*)(A + (size_t)(m0 + ar) * K + k0 + ak);
    float4 a1 = *(const float4*)(A + (size_t)(m0 + ar + 64) * K + k0 + ak);
    const int kr0 = k0 + bk, kr1 = k0 + bk + 8;
    float4 b0 = (kr0 < Kreal) ? *(const float4*)(W + (size_t)kr0 * N + n0 + bc) : zero4;
    float4 b1 = (kr1 < Kreal) ? *(const float4*)(W + (size_t)kr1 * N + n0 + bc) : zero4;

    __syncthreads();
    As[ak + 0][ar] = a0.x; As[ak + 1][ar] = a0.y;
    As[ak + 2][ar] = a0.z; As[ak + 3][ar] = a0.w;
    As[ak + 0][ar + 64] = a1.x; As[ak + 1][ar + 64] = a1.y;
    As[ak + 2][ar + 64] = a1.z; As[ak + 3][ar + 64] = a1.w;
    *(float4*)&Bs[bk][bc]     = b0;
    *(float4*)&Bs[bk + 8][bc] = b1;
    __syncthreads();

    #pragma unroll
    for (int kk = 0; kk < 16; ++kk) {
      const float4 av0 = *(const float4*)&As[kk][ty * 4];
      const float4 av1 = *(const float4*)&As[kk][ty * 4 + 64];
      const float4 bv0 = *(const float4*)&Bs[kk][tx * 4];
      const float4 bv1 = *(const float4*)&Bs[kk][tx * 4 + 64];
      const float am[2][4] = {{av0.x, av0.y, av0.z, av0.w}, {av1.x, av1.y, av1.z, av1.w}};
      const float bn[2][4] = {{bv0.x, bv0.y, bv0.z, bv0.w}, {bv1.x, bv1.y, bv1.z, bv1.w}};
      #pragma unroll
      for (int mi = 0; mi < 2; ++mi)
        #pragma unroll
        for (int ni = 0; ni < 2; ++ni)
          #pragma unroll
          for (int mj = 0; mj < 4; ++mj)
            #pragma unroll
            for (int nj = 0; nj < 4; ++nj)
              acc[mi][ni][mj][nj] += am[mi][mj] * bn[ni][nj];
    }
  }

  const float4 bi0 = *(const float4*)(bias + n0 + tx * 4);
  const float4 bi1 = *(const float4*)(bias + n0 + tx * 4 + 64);
  const float bb[2][4] = {{bi0.x, bi0.y, bi0.z, bi0.w}, {bi1.x, bi1.y, bi1.z, bi1.w}};

  #pragma unroll
  for (int mi = 0; mi < 2; ++mi)
    #pragma unroll
    for (int mj = 0; mj < 4; ++mj) {
      const int m = m0 + mi * 64 + ty * 4 + mj;
      #pragma unroll
      for (int ni = 0; ni < 2; ++ni) {
        float4 o;
        o.x = alpha * acc[mi][ni][mj][0] + bb[ni][0];
        o.y = alpha * acc[mi][ni][mj][1] + bb[ni][1];
        o.z = alpha * acc[mi][ni][mj][2] + bb[ni][2];
        o.w = alpha * acc[mi][ni][mj][3] + bb[ni][3];
        *(float4*)(C + (size_t)m * N + n0 + ni * 64 + tx * 4) = o;
      }
    }
}

// ------------------------------------------------------------------
__global__ __launch_bounds__(512) void esq_kernel(const float* __restrict__ emb,
                                                  float* __restrict__ esq)
{
  const int k = threadIdx.x;
  float s = 0.0f;
  for (int d = 0; d < DD; ++d) { const float v = emb[(size_t)d * KC + k]; s += v * v; }
  esq[k] = s;
}

__global__ __launch_bounds__(256) void transpose_kernel(const float* __restrict__ emb,
                                                        float* __restrict__ embT)
{
  const int t = blockIdx.x * 256 + threadIdx.x;
  const int d = t & (DD - 1);
  const int k = t >> 10;
  embT[t] = emb[(size_t)d * KC + k];
}

// ------------------------------------------------------------------
__global__ __launch_bounds__(64) void argmin_kernel(const float* __restrict__ S,
                                                    int* __restrict__ idx,
                                                    int* __restrict__ cnt)
{
  const int i = blockIdx.x;
  const int lane = threadIdx.x;
  const float* row = S + (size_t)i * KC;
  float best = 3.4e38f;
  int   bi   = 0x7fffffff;
  for (int k = lane; k < KC; k += 64) {
    const float v = row[k];
    if (v < best) { best = v; bi = k; }
  }
  #pragma unroll
  for (int off = 32; off > 0; off >>= 1) {
    const float ov = __shfl_down(best, off);
    const int   oi = __shfl_down(bi, off);
    if (ov < best || (ov == best && oi < bi)) { best = ov; bi = oi; }
  }
  if (lane == 0) { idx[i] = bi; atomicAdd(cnt + bi, 1); }
}

// ------------------------------------------------------------------
__global__ __launch_bounds__(512) void prefix_kernel(const int* __restrict__ cnt,
                                                     int* __restrict__ offs,
                                                     int* __restrict__ cursor)
{
  __shared__ int s[512];
  const int t = threadIdx.x;
  s[t] = cnt[t]; __syncthreads();
  for (int d = 1; d < 512; d <<= 1) {
    const int v = (t >= d) ? s[t - d] : 0;
    __syncthreads();
    s[t] += v;
    __syncthreads();
  }
  const int excl = (t == 0) ? 0 : s[t - 1];
  offs[t] = excl;
  cursor[t] = excl;
}

__global__ __launch_bounds__(256) void scatter_kernel(const int* __restrict__ idx,
                                                      int* __restrict__ cursor,
                                                      int* __restrict__ rows)
{
  const int i = blockIdx.x * 256 + threadIdx.x;
  const int k = idx[i];
  const int slot = atomicAdd(cursor + k, 1);
  rows[slot] = i;
}

// ------------------------------------------------------------------
__global__ __launch_bounds__(512) void finalize_cs_kernel(const int* __restrict__ cnt,
    const float* __restrict__ ecs,
    float* __restrict__ out_perp, float* __restrict__ out_cs, float* __restrict__ ws_cs)
{
  const int t = threadIdx.x;
  __shared__ float red[512];
  const float c  = (float)cnt[t];
  const float cs = F_DECAY * ecs[t] + F_OMD * c;
  red[t] = cs; __syncthreads();
  for (int s = 256; s > 0; s >>= 1) { if (t < s) red[t] += red[t + s]; __syncthreads(); }
  const float n = red[0]; __syncthreads();
  const float css = (cs + F_EPS) / (n + (float)KC * F_EPS) * n;
  out_cs[t] = css;
  ws_cs[t]  = css;
  const float p = c * (1.0f / (float)BB);
  red[t] = p * logf(p + 1e-10f); __syncthreads();
  for (int s = 256; s > 0; s >>= 1) { if (t < s) red[t] += red[t + s]; __syncthreads(); }
  if (t == 0) *out_perp = expf(-red[0]);
}

__global__ void finalize_loss_kernel(const float* __restrict__ lsum,
                                     float* __restrict__ out_loss)
{
  *out_loss = F_CC * lsum[0] * (1.0f / ((float)BB * (float)DD));
}

// ------------------------------------------------------------------
__global__ __launch_bounds__(256) void dw3_partial_kernel(const int* __restrict__ rows,
    const int* __restrict__ offs, const int* __restrict__ cnt,
    const float* __restrict__ z, float* __restrict__ dwacc)
{
  const int k = blockIdx.x;
  const int s = blockIdx.y;
  const int c = cnt[k];
  const int begin = s * 256;
  if (begin >= c) return;
  const int nrows = min(c - begin, 256);
  const int o = offs[k] + begin;
  const int t = threadIdx.x;

  __shared__ int rlist[256];
  if (t < nrows) rlist[t] = rows[o + t];
  __syncthreads();

  float a0 = 0.f, a1 = 0.f, a2 = 0.f, a3 = 0.f;
  for (int r = 0; r < nrows; ++r) {
    const float* zr = z + (size_t)rlist[r] * DD;
    a0 += zr[t]; a1 += zr[t + 256]; a2 += zr[t + 512]; a3 += zr[t + 768];
  }
  atomicAdd(&dwacc[(size_t)(t      ) * KC + k], a0);
  atomicAdd(&dwacc[(size_t)(t + 256) * KC + k], a1);
  atomicAdd(&dwacc[(size_t)(t + 512) * KC + k], a2);
  atomicAdd(&dwacc[(size_t)(t + 768) * KC + k], a3);
}

__global__ __launch_bounds__(256) void dw3_final_kernel(const float* __restrict__ dwacc,
    const float* __restrict__ edw, const float* __restrict__ wcs,
    float* __restrict__ out_emb)
{
  const size_t t = (size_t)blockIdx.x * 256 + threadIdx.x;  // t = d*KC + k
  const int k = (int)(t & (KC - 1));
  out_emb[t] = (F_DECAY * edw[t] + F_OMD * dwacc[t]) / wcs[k];
}

// ------------------------------------------------------------------
__global__ __launch_bounds__(256) void gather_kernel(const int* __restrict__ idx,
    const float* __restrict__ embT, float* zq, float* __restrict__ lsum)
{
  const int i = blockIdx.x;
  const int t = threadIdx.x;
  const int id = idx[i];
  const float4 q  = *(const float4*)(embT + (size_t)id * DD + t * 4);
  const float4 zv = *(const float4*)(zq   + (size_t)i  * DD + t * 4);
  *(float4*)(zq + (size_t)i * DD + t * 4) = q;
  const float dx = q.x - zv.x, dy = q.y - zv.y, dz = q.z - zv.z, dw = q.w - zv.w;
  float s = dx * dx + dy * dy + dz * dz + dw * dw;

  __shared__ float red[256];
  red[t] = s; __syncthreads();
  for (int st = 128; st > 0; st >>= 1) { if (t < st) red[t] += red[t + st]; __syncthreads(); }
  if (t == 0) atomicAdd(lsum, red[0]);
}

// ------------------------------------------------------------------
extern "C" void kernel_launch(void* const* d_in, const int* in_sizes, int n_in,
                              void* d_out, int out_size, void* d_ws, size_t ws_size,
                              hipStream_t stream)
{
  const float* obs  = (const float*)d_in[0];
  const float* act  = (const float*)d_in[1];
  const float* nobs = (const float*)d_in[2];
  const float* rew  = (const float*)d_in[3];
  const float* term = (const float*)d_in[4];
  const float* w0 = (const float*)d_in[5];  const float* b0 = (const float*)d_in[6];
  const float* w1 = (const float*)d_in[7];  const float* b1 = (const float*)d_in[8];
  const float* w2 = (const float*)d_in[9];  const float* b2 = (const float*)d_in[10];
  const float* w3 = (const float*)d_in[11]; const float* b3 = (const float*)d_in[12];
  const float* wl = (const float*)d_in[13]; const float* bl = (const float*)d_in[14];
  const float* emb = (const float*)d_in[15];
  const float* ecs = (const float*)d_in[16];
  const float* edw = (const float*)d_in[17];

  // ---- workspace layout (floats) — identical to round-0, proven to fit ----
  float* ws   = (float*)d_ws;
  float* bufX = ws;                               // MC*K0P  = 2,293,760
  float* bufA = bufX + (size_t)MC * K0P;          // MC*HH   = 8,388,608
  float* bufB = bufA + (size_t)MC * HH;           // MC*HH   = 8,388,608
  // post-MLP overlays:
  float* S    = bufA;                             // BB*KC = 8,388,608 (exact fit)
  float* esq  = bufB;                             // KC
  float* embT = esq + KC;                         // KC*DD
  int*   idx  = (int*)(embT + (size_t)KC * DD);   // BB
  int*   cnt  = idx + BB;                         // KC
  float* lsum = (float*)(cnt + KC);               // 1
  float* wcs  = lsum + 1;                         // KC
  int*   offs = (int*)(wcs + KC);                 // KC
  int*   curs = offs + KC;                        // KC
  int*   rows = curs + KC;                        // BB
  float* dwacc= (float*)(rows + BB);              // DD*KC  (tail total ~1.08M < 8.38M)

  float* out      = (float*)d_out;
  float* zq       = out;                          // z here; gather overwrites with q_st
  float* out_loss = out + (size_t)BB * DD;
  float* out_perp = out_loss + 1;
  float* out_emb  = out_perp + 1;
  float* out_cs   = out_emb + (size_t)DD * KC;

  const dim3 blk(256);

  // ---- MLP in batch chunks (emulated-fp32 fp16x2 MFMA GEMMs) ----
  for (int c = 0; c < NCH; ++c) {
    const size_t c0 = (size_t)c * MC;
    build_x0_kernel<<<dim3(MC), blk, 0, stream>>>(obs + c0 * NOBS, act + c0 * NACT,
                                                  nobs + c0 * NOBS, rew + c0, term + c0, bufX);
    gemm_f16x2_kernel<true ><<<dim3(HH/128, MC/128), blk, 0, stream>>>(bufX, w0, b0, bufA, MC, HH, K0P, DIN);
    gemm_f16x2_kernel<true ><<<dim3(HH/128, MC/128), blk, 0, stream>>>(bufA, w1, b1, bufB, MC, HH, HH,  HH);
    gemm_f16x2_kernel<true ><<<dim3(HH/128, MC/128), blk, 0, stream>>>(bufB, w2, b2, bufA, MC, HH, HH,  HH);
    gemm_f16x2_kernel<true ><<<dim3(HH/128, MC/128), blk, 0, stream>>>(bufA, w3, b3, bufB, MC, HH, HH,  HH);
    gemm_f16x2_kernel<false><<<dim3(DD/128, MC/128), blk, 0, stream>>>(bufB, wl, bl, zq + c0 * DD, MC, DD, HH, HH);
  }

  // ---- VQ phase ----
  init_kernel<<<1, 512, 0, stream>>>(cnt, lsum);
  zero_kernel<<<dim3((DD * KC) / 256), blk, 0, stream>>>(dwacc, DD * KC);
  esq_kernel<<<1, 512, 0, stream>>>(emb, esq);
  sgemm_kernel<<<dim3(KC/128, BB/128), blk, 0, stream>>>(zq, emb, esq, S, BB, KC, DD, DD, -2.0f);
  argmin_kernel<<<dim3(BB), dim3(64), 0, stream>>>(S, idx, cnt);
  prefix_kernel<<<1, 512, 0, stream>>>(cnt, offs, curs);
  scatter_kernel<<<dim3(BB/256), blk, 0, stream>>>(idx, curs, rows);
  finalize_cs_kernel<<<1, 512, 0, stream>>>(cnt, ecs, out_perp, out_cs, wcs);
  dw3_partial_kernel<<<dim3(KC, BB/256), blk, 0, stream>>>(rows, offs, cnt, zq, dwacc);
  dw3_final_kernel<<<dim3((DD*KC)/256), blk, 0, stream>>>(dwacc, edw, wcs, out_emb);
  transpose_kernel<<<dim3((KC*DD)/256), blk, 0, stream>>>(emb, embT);
  gather_kernel<<<dim3(BB), blk, 0, stream>>>(idx, embT, zq, lsum);
  finalize_loss_kernel<<<1, 1, 0, stream>>>(lsum, out_loss);
}

// Round 3
// 19701.849 us; speedup vs baseline: 1.6866x; 1.6866x over previous
//
#include <hip/hip_runtime.h>
#include <math.h>

// Problem constants (match reference)
#define BB   16384
#define NOBS 512
#define NACT 64
#define DIN  1090      // 512+64+512+1+1
#define K0P  1120      // DIN padded to multiple of 32 (zeros)
#define HH   4096
#define DD   1024
#define KC   512

#define MC   2048      // batch chunk rows for the MLP
#define NCH  (BB / MC) // 8 chunks

#define F_DECAY 0.99f
#define F_OMD   0.01f
#define F_CC    0.25f
#define F_EPS   1e-5f

// fp32 emulation via fp16x2 split, 3 MFMA products (hh, hm, mh; mm dropped).
// W is pre-scaled by WSCALE (exact pow2) so fp16 high parts are O(1);
// residuals are scaled by RSCALE (exact pow2) to stay in fp16 NORMAL range
// and accumulated in a second accumulator: x*w = (acc0 + acc1/RSCALE)/WSCALE.
// Numerics identical to rounds 1-2 (proven absmax 9.77e-4, same as baseline).
#define WSCALE   64.0f
#define WINV     0.015625f       // 1/64
#define RSCALE   2048.0f
#define RINV     4.8828125e-4f   // 1/2048

using half8 = __attribute__((ext_vector_type(8))) _Float16;  // MFMA A/B frag (4 VGPRs)
using f4v   = __attribute__((ext_vector_type(4))) float;     // MFMA C/D frag

static __device__ inline void split2(float x, _Float16& h, _Float16& m) {
  h = (_Float16)x;                              // RNE
  m = (_Float16)((x - (float)h) * RSCALE);      // x-h exact in fp32; *2048 exact
}

// ------------------------------------------------------------------
// Build one chunk of X0 = hstack(obs, action, next_obs, reward, term), padded.
// ------------------------------------------------------------------
__global__ __launch_bounds__(256) void build_x0_kernel(
    const float* __restrict__ obs, const float* __restrict__ act,
    const float* __restrict__ nobs, const float* __restrict__ rew,
    const float* __restrict__ term, float* __restrict__ X0)
{
  const int i = blockIdx.x;
  const int t = threadIdx.x;
  float* row = X0 + (size_t)i * K0P;
  for (int c = t; c < K0P; c += 256) {
    float v;
    if (c < NOBS)                 v = obs[(size_t)i * NOBS + c];
    else if (c < NOBS + NACT)     v = act[(size_t)i * NACT + (c - NOBS)];
    else if (c < 2*NOBS + NACT)   v = nobs[(size_t)i * NOBS + (c - NOBS - NACT)];
    else if (c == 1088)           v = rew[i];
    else if (c == 1089)           v = term[i];
    else                          v = 0.0f;
    row[c] = v;
  }
}

__global__ void init_kernel(int* __restrict__ cnt, float* __restrict__ lsum)
{
  const int t = threadIdx.x;
  if (t < KC) cnt[t] = 0;
  if (t == 0) *lsum = 0.0f;
}

__global__ __launch_bounds__(256) void zero_kernel(float* __restrict__ p, int n)
{
  const int i = blockIdx.x * 256 + threadIdx.x;
  if (i < n) p[i] = 0.0f;
}

// ------------------------------------------------------------------
// Emulated-fp32 GEMM via fp16x2 split + MFMA (3 products).
// REGISTER-LEAN tiling: 512 threads = 8 waves (2m x 4n), wave tile 64x32
// -> acc0+acc1 = 4x2x2 f4v = 64 AGPRs/wave (vs 128 in the round-2 version
// whose 240-reg/wave footprint broke the compiler's load-hoisting pipeline).
// Total regs ~170/wave: headroom under the 256-reg / 2-waves-per-SIMD cliff
// restores software pipelining of next-iter global loads over the MFMAs.
// BM=BN=128, BK=32. LDS: [comp][kgroup][row][8] f16, k-contiguous per lane
// (16B/lane ds_read_b128). Per-thread staging: 8 A floats + 8 B floats.
// ------------------------------------------------------------------
template<bool RELU>
__global__ __launch_bounds__(512, 2) void gemm_f16x2_kernel(
    const float* __restrict__ A, const float* __restrict__ W,
    const float* __restrict__ bias, float* __restrict__ C,
    int M, int N, int K, int Kreal)
{
  __shared__ __align__(16) _Float16 Alds[2][4][128][8];   // 16 KB
  __shared__ __align__(16) _Float16 Blds[2][4][128][8];   // 16 KB

  const int tid = threadIdx.x;
  const int n0 = blockIdx.x * 128;
  const int m0 = blockIdx.y * 128;

  // A staging: thread -> (row sam, k-octet saq)
  const int sam = tid >> 2;          // 0..127
  const int saq = tid & 3;           // 0..3  (k-octet = LDS kgroup)
  // B staging: thread -> (col sbn, k-octet sbg)
  const int sbn = tid & 127;         // 0..127
  const int sbg = tid >> 7;          // 0..3

  const int lane = tid & 63;
  const int wv   = tid >> 6;             // wave 0..7 (2m x 4n)
  const int wmo  = (wv >> 2) * 64;
  const int wno  = (wv & 3) * 32;
  const int lm   = lane & 15;            // m (A) / n (B) / col (C)
  const int kg   = lane >> 4;            // k-group 0..3 (8 k each)

  f4v acc0[4][2], acc1[4][2];
  #pragma unroll
  for (int a = 0; a < 4; ++a)
    #pragma unroll
    for (int b = 0; b < 2; ++b) { acc0[a][b] = (f4v)0.0f; acc1[a][b] = (f4v)0.0f; }

  const float* Arow = A + (size_t)(m0 + sam) * K + saq * 8;

  for (int k0 = 0; k0 < K; k0 += 32) {
    // A: 2 x float4 (one row-octet per thread)
    const float4 a0 = *(const float4*)(Arow + k0);
    const float4 a1 = *(const float4*)(Arow + k0 + 4);
    // B: 8 coalesced fp32 loads (consecutive tid -> consecutive n)
    float bv[8];
    #pragma unroll
    for (int i = 0; i < 8; ++i) {
      const int kk = k0 + sbg * 8 + i;
      bv[i] = (kk < Kreal) ? W[(size_t)kk * N + n0 + sbn] * WSCALE : 0.0f;
    }

    __syncthreads();   // previous iteration's fragment reads complete

    {
      const float xs[8] = {a0.x, a0.y, a0.z, a0.w, a1.x, a1.y, a1.z, a1.w};
      half8 hh, mm;
      #pragma unroll
      for (int j = 0; j < 8; ++j) {
        _Float16 h, m; split2(xs[j], h, m);
        hh[j] = h; mm[j] = m;
      }
      *(half8*)&Alds[0][saq][sam][0] = hh;
      *(half8*)&Alds[1][saq][sam][0] = mm;
    }
    {
      half8 vh, vm;
      #pragma unroll
      for (int i = 0; i < 8; ++i) {
        _Float16 h, m; split2(bv[i], h, m);
        vh[i] = h; vm[i] = m;
      }
      *(half8*)&Blds[0][sbg][sbn][0] = vh;
      *(half8*)&Blds[1][sbg][sbn][0] = vm;
    }
    __syncthreads();

    half8 bh[2], bm[2];
    #pragma unroll
    for (int nt = 0; nt < 2; ++nt) {
      bh[nt] = *(const half8*)&Blds[0][kg][wno + nt * 16 + lm][0];
      bm[nt] = *(const half8*)&Blds[1][kg][wno + nt * 16 + lm][0];
    }
    #pragma unroll
    for (int mt = 0; mt < 4; ++mt) {
      const half8 ah = *(const half8*)&Alds[0][kg][wmo + mt * 16 + lm][0];
      const half8 am = *(const half8*)&Alds[1][kg][wmo + mt * 16 + lm][0];
      #pragma unroll
      for (int nt = 0; nt < 2; ++nt) {
        acc0[mt][nt] = __builtin_amdgcn_mfma_f32_16x16x32_f16(ah, bh[nt], acc0[mt][nt], 0, 0, 0); // hi*hi
        acc1[mt][nt] = __builtin_amdgcn_mfma_f32_16x16x32_f16(ah, bm[nt], acc1[mt][nt], 0, 0, 0); // hi*res
        acc1[mt][nt] = __builtin_amdgcn_mfma_f32_16x16x32_f16(am, bh[nt], acc1[mt][nt], 0, 0, 0); // res*hi
      }
    }
  }

  float bias_v[2];
  #pragma unroll
  for (int nt = 0; nt < 2; ++nt) bias_v[nt] = bias[n0 + wno + nt * 16 + lm];

  #pragma unroll
  for (int mt = 0; mt < 4; ++mt)
    #pragma unroll
    for (int nt = 0; nt < 2; ++nt) {
      const int n = n0 + wno + nt * 16 + lm;
      #pragma unroll
      for (int r = 0; r < 4; ++r) {
        const int m = m0 + wmo + mt * 16 + kg * 4 + r;
        float v = (acc0[mt][nt][r] + acc1[mt][nt][r] * RINV) * WINV + bias_v[nt];
        if (RELU) v = fmaxf(v, 0.0f);
        C[(size_t)m * N + n] = v;
      }
    }
}

// ------------------------------------------------------------------
// fp32 vector GEMM (scores GEMM only)
// ------------------------------------------------------------------
__global__ __launch_bounds__(256) void sgemm_kernel(
    const float* __restrict__ A, const float* __restrict__ W,
    const float* __restrict__ bias, float* __restrict__ C,
    int M, int N, int K, int Kreal, float alpha)
{
  __shared__ float As[16][128];
  __shared__ float Bs[16][128];

  const int tid = threadIdx.x;
  const int n0 = blockIdx.x * 128;
  const int m0 = blockIdx.y * 128;

  const int ar = tid & 63;
  const int ak = (tid >> 6) << 2;
  const int bk = tid >> 5;
  const int bc = (tid & 31) << 2;
  const int tx = tid & 15;
  const int ty = tid >> 4;

  float acc[2][2][4][4];
  #pragma unroll
  for (int a = 0; a < 2; ++a)
    #pragma unroll
    for (int b = 0; b < 2; ++b)
      #pragma unroll
      for (int c = 0; c < 4; ++c)
        #pragma unroll
        for (int d = 0; d < 4; ++d) acc[a][b][c][d] = 0.0f;

  const float4 zero4 = make_float4(0.f, 0.f, 0.f, 0.f);

  for (int k0 = 0; k0 < K; k0 += 16) {
    float4 a0 = *(const float4*)(A + (size_t)(m0 + ar) * K + k0 + ak);
    float4 a1 = *(const float4*)(A + (size_t)(m0 + ar + 64) * K + k0 + ak);
    const int kr0 = k0 + bk, kr1 = k0 + bk + 8;
    float4 b0 = (kr0 < Kreal) ? *(const float4*)(W + (size_t)kr0 * N + n0 + bc) : zero4;
    float4 b1 = (kr1 < Kreal) ? *(const float4*)(W + (size_t)kr1 * N + n0 + bc) : zero4;

    __syncthreads();
    As[ak + 0][ar] = a0.x; As[ak + 1][ar] = a0.y;
    As[ak + 2][ar] = a0.z; As[ak + 3][ar] = a0.w;
    As[ak + 0][ar + 64] = a1.x; As[ak + 1][ar + 64] = a1.y;
    As[ak + 2][ar + 64] = a1.z; As[ak + 3][ar + 64] = a1.w;
    *(float4*)&Bs[bk][bc]     = b0;
    *(float4*)&Bs[bk + 8][bc] = b1;
    __syncthreads();

    #pragma unroll
    for (int kk = 0; kk < 16; ++kk) {
      const float4 av0 = *(const float4*)&As[kk][ty * 4];
      const float4 av1 = *(const float4*)&As[kk][ty * 4 + 64];
      const float4 bv0 = *(const float4*)&Bs[kk][tx * 4];
      const float4 bv1 = *(const float4*)&Bs[kk][tx * 4 + 64];
      const float am[2][4] = {{av0.x, av0.y, av0.z, av0.w}, {av1.x, av1.y, av1.z, av1.w}};
      const float bn[2][4] = {{bv0.x, bv0.y, bv0.z, bv0.w}, {bv1.x, bv1.y, bv1.z, bv1.w}};
      #pragma unroll
      for (int mi = 0; mi < 2; ++mi)
        #pragma unroll
        for (int ni = 0; ni < 2; ++ni)
          #pragma unroll
          for (int mj = 0; mj < 4; ++mj)
            #pragma unroll
            for (int nj = 0; nj < 4; ++nj)
              acc[mi][ni][mj][nj] += am[mi][mj] * bn[ni][nj];
    }
  }

  const float4 bi0 = *(const float4*)(bias + n0 + tx * 4);
  const float4 bi1 = *(const float4*)(bias + n0 + tx * 4 + 64);
  const float bb[2][4] = {{bi0.x, bi0.y, bi0.z, bi0.w}, {bi1.x, bi1.y, bi1.z, bi1.w}};

  #pragma unroll
  for (int mi = 0; mi < 2; ++mi)
    #pragma unroll
    for (int mj = 0; mj < 4; ++mj) {
      const int m = m0 + mi * 64 + ty * 4 + mj;
      #pragma unroll
      for (int ni = 0; ni < 2; ++ni) {
        float4 o;
        o.x = alpha * acc[mi][ni][mj][0] + bb[ni][0];
        o.y = alpha * acc[mi][ni][mj][1] + bb[ni][1];
        o.z = alpha * acc[mi][ni][mj][2] + bb[ni][2];
        o.w = alpha * acc[mi][ni][mj][3] + bb[ni][3];
        *(float4*)(C + (size_t)m * N + n0 + ni * 64 + tx * 4) = o;
      }
    }
}

// ------------------------------------------------------------------
__global__ __launch_bounds__(512) void esq_kernel(const float* __restrict__ emb,
                                                  float* __restrict__ esq)
{
  const int k = threadIdx.x;
  float s = 0.0f;
  for (int d = 0; d < DD; ++d) { const float v = emb[(size_t)d * KC + k]; s += v * v; }
  esq[k] = s;
}

__global__ __launch_bounds__(256) void transpose_kernel(const float* __restrict__ emb,
                                                        float* __restrict__ embT)
{
  const int t = blockIdx.x * 256 + threadIdx.x;
  const int d = t & (DD - 1);
  const int k = t >> 10;
  embT[t] = emb[(size_t)d * KC + k];
}

// ------------------------------------------------------------------
__global__ __launch_bounds__(64) void argmin_kernel(const float* __restrict__ S,
                                                    int* __restrict__ idx,
                                                    int* __restrict__ cnt)
{
  const int i = blockIdx.x;
  const int lane = threadIdx.x;
  const float* row = S + (size_t)i * KC;
  float best = 3.4e38f;
  int   bi   = 0x7fffffff;
  for (int k = lane; k < KC; k += 64) {
    const float v = row[k];
    if (v < best) { best = v; bi = k; }
  }
  #pragma unroll
  for (int off = 32; off > 0; off >>= 1) {
    const float ov = __shfl_down(best, off);
    const int   oi = __shfl_down(bi, off);
    if (ov < best || (ov == best && oi < bi)) { best = ov; bi = oi; }
  }
  if (lane == 0) { idx[i] = bi; atomicAdd(cnt + bi, 1); }
}

// ------------------------------------------------------------------
__global__ __launch_bounds__(512) void prefix_kernel(const int* __restrict__ cnt,
                                                     int* __restrict__ offs,
                                                     int* __restrict__ cursor)
{
  __shared__ int s[512];
  const int t = threadIdx.x;
  s[t] = cnt[t]; __syncthreads();
  for (int d = 1; d < 512; d <<= 1) {
    const int v = (t >= d) ? s[t - d] : 0;
    __syncthreads();
    s[t] += v;
    __syncthreads();
  }
  const int excl = (t == 0) ? 0 : s[t - 1];
  offs[t] = excl;
  cursor[t] = excl;
}

__global__ __launch_bounds__(256) void scatter_kernel(const int* __restrict__ idx,
                                                      int* __restrict__ cursor,
                                                      int* __restrict__ rows)
{
  const int i = blockIdx.x * 256 + threadIdx.x;
  const int k = idx[i];
  const int slot = atomicAdd(cursor + k, 1);
  rows[slot] = i;
}

// ------------------------------------------------------------------
__global__ __launch_bounds__(512) void finalize_cs_kernel(const int* __restrict__ cnt,
    const float* __restrict__ ecs,
    float* __restrict__ out_perp, float* __restrict__ out_cs, float* __restrict__ ws_cs)
{
  const int t = threadIdx.x;
  __shared__ float red[512];
  const float c  = (float)cnt[t];
  const float cs = F_DECAY * ecs[t] + F_OMD * c;
  red[t] = cs; __syncthreads();
  for (int s = 256; s > 0; s >>= 1) { if (t < s) red[t] += red[t + s]; __syncthreads(); }
  const float n = red[0]; __syncthreads();
  const float css = (cs + F_EPS) / (n + (float)KC * F_EPS) * n;
  out_cs[t] = css;
  ws_cs[t]  = css;
  const float p = c * (1.0f / (float)BB);
  red[t] = p * logf(p + 1e-10f); __syncthreads();
  for (int s = 256; s > 0; s >>= 1) { if (t < s) red[t] += red[t + s]; __syncthreads(); }
  if (t == 0) *out_perp = expf(-red[0]);
}

__global__ void finalize_loss_kernel(const float* __restrict__ lsum,
                                     float* __restrict__ out_loss)
{
  *out_loss = F_CC * lsum[0] * (1.0f / ((float)BB * (float)DD));
}

// ------------------------------------------------------------------
__global__ __launch_bounds__(256) void dw3_partial_kernel(const int* __restrict__ rows,
    const int* __restrict__ offs, const int* __restrict__ cnt,
    const float* __restrict__ z, float* __restrict__ dwacc)
{
  const int k = blockIdx.x;
  const int s = blockIdx.y;
  const int c = cnt[k];
  const int begin = s * 256;
  if (begin >= c) return;
  const int nrows = min(c - begin, 256);
  const int o = offs[k] + begin;
  const int t = threadIdx.x;

  __shared__ int rlist[256];
  if (t < nrows) rlist[t] = rows[o + t];
  __syncthreads();

  float a0 = 0.f, a1 = 0.f, a2 = 0.f, a3 = 0.f;
  for (int r = 0; r < nrows; ++r) {
    const float* zr = z + (size_t)rlist[r] * DD;
    a0 += zr[t]; a1 += zr[t + 256]; a2 += zr[t + 512]; a3 += zr[t + 768];
  }
  atomicAdd(&dwacc[(size_t)(t      ) * KC + k], a0);
  atomicAdd(&dwacc[(size_t)(t + 256) * KC + k], a1);
  atomicAdd(&dwacc[(size_t)(t + 512) * KC + k], a2);
  atomicAdd(&dwacc[(size_t)(t + 768) * KC + k], a3);
}

__global__ __launch_bounds__(256) void dw3_final_kernel(const float* __restrict__ dwacc,
    const float* __restrict__ edw, const float* __restrict__ wcs,
    float* __restrict__ out_emb)
{
  const size_t t = (size_t)blockIdx.x * 256 + threadIdx.x;  // t = d*KC + k
  const int k = (int)(t & (KC - 1));
  out_emb[t] = (F_DECAY * edw[t] + F_OMD * dwacc[t]) / wcs[k];
}

// ------------------------------------------------------------------
__global__ __launch_bounds__(256) void gather_kernel(const int* __restrict__ idx,
    const float* __restrict__ embT, float* zq, float* __restrict__ lsum)
{
  const int i = blockIdx.x;
  const int t = threadIdx.x;
  const int id = idx[i];
  const float4 q  = *(const float4*)(embT + (size_t)id * DD + t * 4);
  const float4 zv = *(const float4*)(zq   + (size_t)i  * DD + t * 4);
  *(float4*)(zq + (size_t)i * DD + t * 4) = q;
  const float dx = q.x - zv.x, dy = q.y - zv.y, dz = q.z - zv.z, dw = q.w - zv.w;
  float s = dx * dx + dy * dy + dz * dz + dw * dw;

  __shared__ float red[256];
  red[t] = s; __syncthreads();
  for (int st = 128; st > 0; st >>= 1) { if (t < st) red[t] += red[t + st]; __syncthreads(); }
  if (t == 0) atomicAdd(lsum, red[0]);
}

// ------------------------------------------------------------------
extern "C" void kernel_launch(void* const* d_in, const int* in_sizes, int n_in,
                              void* d_out, int out_size, void* d_ws, size_t ws_size,
                              hipStream_t stream)
{
  const float* obs  = (const float*)d_in[0];
  const float* act  = (const float*)d_in[1];
  const float* nobs = (const float*)d_in[2];
  const float* rew  = (const float*)d_in[3];
  const float* term = (const float*)d_in[4];
  const float* w0 = (const float*)d_in[5];  const float* b0 = (const float*)d_in[6];
  const float* w1 = (const float*)d_in[7];  const float* b1 = (const float*)d_in[8];
  const float* w2 = (const float*)d_in[9];  const float* b2 = (const float*)d_in[10];
  const float* w3 = (const float*)d_in[11]; const float* b3 = (const float*)d_in[12];
  const float* wl = (const float*)d_in[13]; const float* bl = (const float*)d_in[14];
  const float* emb = (const float*)d_in[15];
  const float* ecs = (const float*)d_in[16];
  const float* edw = (const float*)d_in[17];

  // ---- workspace layout (floats) — identical to round-0, proven to fit ----
  float* ws   = (float*)d_ws;
  float* bufX = ws;                               // MC*K0P  = 2,293,760
  float* bufA = bufX + (size_t)MC * K0P;          // MC*HH   = 8,388,608
  float* bufB = bufA + (size_t)MC * HH;           // MC*HH   = 8,388,608
  // post-MLP overlays:
  float* S    = bufA;                             // BB*KC = 8,388,608 (exact fit)
  float* esq  = bufB;                             // KC
  float* embT = esq + KC;                         // KC*DD
  int*   idx  = (int*)(embT + (size_t)KC * DD);   // BB
  int*   cnt  = idx + BB;                         // KC
  float* lsum = (float*)(cnt + KC);               // 1
  float* wcs  = lsum + 1;                         // KC
  int*   offs = (int*)(wcs + KC);                 // KC
  int*   curs = offs + KC;                        // KC
  int*   rows = curs + KC;                        // BB
  float* dwacc= (float*)(rows + BB);              // DD*KC  (tail total ~1.08M < 8.38M)

  float* out      = (float*)d_out;
  float* zq       = out;                          // z here; gather overwrites with q_st
  float* out_loss = out + (size_t)BB * DD;
  float* out_perp = out_loss + 1;
  float* out_emb  = out_perp + 1;
  float* out_cs   = out_emb + (size_t)DD * KC;

  const dim3 blk(256);
  const dim3 blk512(512);

  // ---- MLP in batch chunks (emulated-fp32 fp16x2 MFMA GEMMs) ----
  for (int c = 0; c < NCH; ++c) {
    const size_t c0 = (size_t)c * MC;
    build_x0_kernel<<<dim3(MC), blk, 0, stream>>>(obs + c0 * NOBS, act + c0 * NACT,
                                                  nobs + c0 * NOBS, rew + c0, term + c0, bufX);
    gemm_f16x2_kernel<true ><<<dim3(HH/128, MC/128), blk512, 0, stream>>>(bufX, w0, b0, bufA, MC, HH, K0P, DIN);
    gemm_f16x2_kernel<true ><<<dim3(HH/128, MC/128), blk512, 0, stream>>>(bufA, w1, b1, bufB, MC, HH, HH,  HH);
    gemm_f16x2_kernel<true ><<<dim3(HH/128, MC/128), blk512, 0, stream>>>(bufB, w2, b2, bufA, MC, HH, HH,  HH);
    gemm_f16x2_kernel<true ><<<dim3(HH/128, MC/128), blk512, 0, stream>>>(bufA, w3, b3, bufB, MC, HH, HH,  HH);
    gemm_f16x2_kernel<false><<<dim3(DD/128, MC/128), blk512, 0, stream>>>(bufB, wl, bl, zq + c0 * DD, MC, DD, HH, HH);
  }

  // ---- VQ phase ----
  init_kernel<<<1, 512, 0, stream>>>(cnt, lsum);
  zero_kernel<<<dim3((DD * KC) / 256), blk, 0, stream>>>(dwacc, DD * KC);
  esq_kernel<<<1, 512, 0, stream>>>(emb, esq);
  sgemm_kernel<<<dim3(KC/128, BB/128), blk, 0, stream>>>(zq, emb, esq, S, BB, KC, DD, DD, -2.0f);
  argmin_kernel<<<dim3(BB), dim3(64), 0, stream>>>(S, idx, cnt);
  prefix_kernel<<<1, 512, 0, stream>>>(cnt, offs, curs);
  scatter_kernel<<<dim3(BB/256), blk, 0, stream>>>(idx, curs, rows);
  finalize_cs_kernel<<<1, 512, 0, stream>>>(cnt, ecs, out_perp, out_cs, wcs);
  dw3_partial_kernel<<<dim3(KC, BB/256), blk, 0, stream>>>(rows, offs, cnt, zq, dwacc);
  dw3_final_kernel<<<dim3((DD*KC)/256), blk, 0, stream>>>(dwacc, edw, wcs, out_emb);
  transpose_kernel<<<dim3((KC*DD)/256), blk, 0, stream>>>(emb, embT);
  gather_kernel<<<dim3(BB), blk, 0, stream>>>(idx, embT, zq, lsum);
  finalize_loss_kernel<<<1, 1, 0, stream>>>(lsum, out_loss);
}